// Round 3
// baseline (423.421 us; speedup 1.0000x reference)
//
#include <hip/hip_runtime.h>
#include <math.h>

// Problem constants (fixed by reference): B=64, N=512, D=64, H=4, C=64, L=3
// Workspace layout (floats):
//   xbuf [0 .. 2097152)            : layer activations x (B*N*64) = 8 MB
//     -- prep metadata (3 MB) is overlaid at the FRONT of xbuf between
//        lin (reads x) and finalize (rewrites x); stream order makes it safe.
//   hbuf [2097152 .. 10485760)     : h (B*N*H*C) = 32 MB; yH aliases h.

// ---------------------------------------------------------------------------
// Kernel A: h[gn][o] = sum_d x[gn][d] * W[o][d]   (gn over B*N, o over 256)
// 128n x 128o tile, XOR-swizzled LDS. d4 loop kept un-unrolled (R1: unrolled
// version spilled at 256 VGPRs -> 9.5x write amplification).
// ---------------------------------------------------------------------------
__global__ __launch_bounds__(256) void lin_kernel(const float* __restrict__ x,
                                                  const float* __restrict__ W,
                                                  float* __restrict__ h) {
    __shared__ float Ws[128 * 64];
    __shared__ float Xs[128 * 64];
    const int tid = threadIdx.x;
    const int nblk = blockIdx.x >> 1;
    const int o0 = (blockIdx.x & 1) * 128;
    const int gn0 = nblk * 128;

#pragma unroll
    for (int q = 0; q < 8; ++q) {
        int flat = q * 256 + tid;
        int row = flat >> 4, d4 = flat & 15;
        float4 v = *(const float4*)(W + (size_t)(o0 + row) * 64 + d4 * 4);
        *(float4*)(Ws + row * 64 + ((d4 ^ ((row >> 3) & 7)) << 2)) = v;
    }
#pragma unroll
    for (int q = 0; q < 8; ++q) {
        int flat = q * 256 + tid;
        int row = flat >> 4, d4 = flat & 15;
        float4 v = *(const float4*)(x + (size_t)(gn0 + row) * 64 + d4 * 4);
        *(float4*)(Xs + row * 64 + ((d4 ^ (row & 7)) << 2)) = v;
    }
    __syncthreads();

    const int og = tid >> 4;
    const int ng = tid & 15;
    const int wsw = og & 7;
    const int xsw = ng & 7;
    float acc[8][8];
#pragma unroll
    for (int k = 0; k < 8; ++k)
#pragma unroll
        for (int j = 0; j < 8; ++j) acc[k][j] = 0.f;

#pragma unroll 1
    for (int d4 = 0; d4 < 16; ++d4) {
        float4 x4[8];
#pragma unroll
        for (int j = 0; j < 8; ++j)
            x4[j] = *(const float4*)(Xs + (ng + 16 * j) * 64 + ((d4 ^ xsw) << 2));
#pragma unroll
        for (int k = 0; k < 8; ++k) {
            float4 w = *(const float4*)(Ws + (og * 8 + k) * 64 + ((d4 ^ wsw) << 2));
#pragma unroll
            for (int j = 0; j < 8; ++j)
                acc[k][j] += w.x * x4[j].x + w.y * x4[j].y +
                             w.z * x4[j].z + w.w * x4[j].w;
        }
    }

#pragma unroll
    for (int j = 0; j < 8; ++j) {
        int gn = gn0 + ng + 16 * j;
        float* dst = h + (size_t)gn * 256 + o0 + og * 8;
        *(float4*)(dst) = make_float4(acc[0][j], acc[1][j], acc[2][j], acc[3][j]);
        *(float4*)(dst + 4) = make_float4(acc[4][j], acc[5][j], acc[6][j], acc[7][j]);
    }
}

// ---------------------------------------------------------------------------
// Kernel B1: attn_prep — per (b,head): s/d dots, bitonic sort of s, exp
// factors, scalar z-scans, per-i crossover + normalizer. Writes metadata.
// ---------------------------------------------------------------------------
__global__ __launch_bounds__(256) void attn_prep(const float* __restrict__ h,
                                                 const float* __restrict__ att_src,
                                                 const float* __restrict__ att_dst,
                                                 int* __restrict__ g_sidx,
                                                 float* __restrict__ g_E1,
                                                 float* __restrict__ g_E2,
                                                 float* __restrict__ g_aZ,
                                                 float* __restrict__ g_bZ,
                                                 int* __restrict__ g_k) {
    const int bh = blockIdx.x;           // b*4 + head
    const int b = bh >> 2;
    const int head = bh & 3;
    const int t = threadIdx.x;

    __shared__ float att_s[64], att_d[64];
    __shared__ float s_val[512];
    __shared__ int   s_idx[512];
    __shared__ float E1[512], E2[512];
    __shared__ float z1suf[513], z2pre[513];
    __shared__ float segs1[64], segs2[64];

    if (t < 64) att_s[t] = att_src[head * 64 + t];
    else if (t < 128) att_d[t - 64] = att_dst[head * 64 + (t - 64)];
    __syncthreads();

    float dreg[2];   // d_i for i = t, t+256 (original index; unaffected by sort)
    for (int rr = 0; rr < 2; ++rr) {
        int j = t + rr * 256;
        const float* hrow = h + ((size_t)(b * 512 + j) * 4 + head) * 64;
        float as = 0.f, ad = 0.f;
#pragma unroll
        for (int d4 = 0; d4 < 16; ++d4) {
            float4 hv = *(const float4*)(hrow + d4 * 4);
            float4 sv = *(const float4*)(att_s + d4 * 4);
            float4 dv = *(const float4*)(att_d + d4 * 4);
            as += hv.x * sv.x + hv.y * sv.y + hv.z * sv.z + hv.w * sv.w;
            ad += hv.x * dv.x + hv.y * dv.y + hv.z * dv.z + hv.w * dv.w;
        }
        s_val[j] = as; s_idx[j] = j; dreg[rr] = ad;
    }
    __syncthreads();

    // Bitonic sort ascending (value + original index)
    for (int k = 2; k <= 512; k <<= 1) {
        for (int j = k >> 1; j > 0; j >>= 1) {
            for (int rr = 0; rr < 2; ++rr) {
                int i = t + rr * 256;
                int l = i ^ j;
                if (l > i) {
                    float a = s_val[i], c = s_val[l];
                    bool up = ((i & k) == 0);
                    if (up ? (a > c) : (a < c)) {
                        s_val[i] = c; s_val[l] = a;
                        int ia = s_idx[i]; s_idx[i] = s_idx[l]; s_idx[l] = ia;
                    }
                }
            }
            __syncthreads();
        }
    }

    const float M = s_val[511];
    for (int rr = 0; rr < 2; ++rr) {
        int r = t + rr * 256;
        float sv = s_val[r] - M;
        float e1 = __expf(sv);
        float e2 = __expf(0.2f * sv);
        E1[r] = e1; E2[r] = e2;
        g_E1[bh * 512 + r] = e1;
        g_E2[bh * 512 + r] = e2;
        g_sidx[bh * 512 + r] = s_idx[r];
    }
    __syncthreads();

    // z1suf[r] = sum_{r'>=r} E1 ; z2pre[r] = sum_{r'<r} E2
    if (t < 64) {
        float p1 = 0.f, p2 = 0.f;
#pragma unroll
        for (int q = 0; q < 8; ++q) { p1 += E1[t * 8 + q]; p2 += E2[t * 8 + q]; }
        segs1[t] = p1; segs2[t] = p2;
    }
    __syncthreads();
    if (t < 64) {
        float suf = 0.f, pre = 0.f;
        for (int s = t + 1; s < 64; ++s) suf += segs1[s];
        for (int s = 0; s < t; ++s) pre += segs2[s];
        float run = suf;
        for (int q = 7; q >= 0; --q) { run += E1[t * 8 + q]; z1suf[t * 8 + q] = run; }
        float run2 = pre;
        for (int q = 0; q < 8; ++q) { z2pre[t * 8 + q] = run2; run2 += E2[t * 8 + q]; }
        if (t == 63) z2pre[512] = run2;
        if (t == 0) z1suf[512] = 0.f;
    }
    __syncthreads();

    // Per-i: crossover k_i (binary search, monotone in sorted s), scales
    for (int rr = 0; rr < 2; ++rr) {
        int i = t + rr * 256;
        float d = dreg[rr];
        int lo = 0, hi = 512;
        while (lo < hi) {
            int mid = (lo + hi) >> 1;
            if (d + s_val[mid] >= 0.f) hi = mid; else lo = mid + 1;
        }
        int k = lo;
        float g = d + M;
        float G = (g >= 0.f) ? g : 0.2f * g;   // denominator >= 1
        float al = __expf(g - G);
        float be = __expf(0.2f * g - G);
        float Z = al * z1suf[k] + be * z2pre[k];
        float inv = 1.0f / Z;
        g_aZ[bh * 512 + i] = al * inv;
        g_bZ[bh * 512 + i] = be * inv;
        g_k[bh * 512 + i]  = k;
    }
}

// ---------------------------------------------------------------------------
// Kernel B2: attn_agg — one block per (b,head, 8-channel group). Gather h in
// sorted order, weighted suffix(E1*h)/prefix(E2*h) scans (register scans,
// channel-major LDS stride 516 -> conflict-light b128), query at k_i.
// yH aliases h: this block is the only toucher of its (bh, channel) columns;
// all its h reads precede the barrier before its yH writes.
// ---------------------------------------------------------------------------
#define AP 516
__global__ __launch_bounds__(256) void attn_agg(const float* __restrict__ h,
                                                const int* __restrict__ g_sidx,
                                                const float* __restrict__ g_E1,
                                                const float* __restrict__ g_E2,
                                                const float* __restrict__ g_aZ,
                                                const float* __restrict__ g_bZ,
                                                const int* __restrict__ g_k,
                                                float* __restrict__ yH) {
    const int bh = blockIdx.x >> 3;      // 0..255
    const int cg = blockIdx.x & 7;       // 0..7
    const int b = bh >> 2, head = bh & 3;
    const int c0 = cg * 8;
    const int t = threadIdx.x;

    __shared__ float A1[8 * AP];         // [channel][sorted r], pad 516
    __shared__ float A2[8 * AP];
    __shared__ float segs1[8 * 33], segs2[8 * 33];
    __shared__ float tot2[8];

    // Phase G: gather + weight
    for (int rr = 0; rr < 2; ++rr) {
        int r = t + rr * 256;
        int j = g_sidx[bh * 512 + r];
        float e1 = g_E1[bh * 512 + r];
        float e2 = g_E2[bh * 512 + r];
        const float* hp = h + ((size_t)(b * 512 + j) * 4 + head) * 64 + c0;
        float4 h0 = *(const float4*)(hp);
        float4 h1 = *(const float4*)(hp + 4);
        float hv[8] = {h0.x, h0.y, h0.z, h0.w, h1.x, h1.y, h1.z, h1.w};
#pragma unroll
        for (int c = 0; c < 8; ++c) {
            A1[c * AP + r] = e1 * hv[c];
            A2[c * AP + r] = e2 * hv[c];
        }
    }
    __syncthreads();

    // Phase S: register scans over 16-row segments
    {
        const int cl = t & 7, seg = t >> 3;
        float* p1 = A1 + cl * AP + seg * 16;
        float* p2 = A2 + cl * AP + seg * 16;
        float v1[16], v2[16];
#pragma unroll
        for (int q4 = 0; q4 < 4; ++q4) {
            float4 a = *(const float4*)(p1 + q4 * 4);
            v1[q4 * 4 + 0] = a.x; v1[q4 * 4 + 1] = a.y; v1[q4 * 4 + 2] = a.z; v1[q4 * 4 + 3] = a.w;
            float4 c = *(const float4*)(p2 + q4 * 4);
            v2[q4 * 4 + 0] = c.x; v2[q4 * 4 + 1] = c.y; v2[q4 * 4 + 2] = c.z; v2[q4 * 4 + 3] = c.w;
        }
        float s1 = 0.f, s2 = 0.f;
#pragma unroll
        for (int q = 0; q < 16; ++q) { s1 += v1[q]; s2 += v2[q]; }
        segs1[cl * 33 + seg] = s1; segs2[cl * 33 + seg] = s2;
        __syncthreads();
        float suf = 0.f, pre = 0.f;
        for (int s = seg + 1; s < 32; ++s) suf += segs1[cl * 33 + s];
        for (int s = 0; s < seg; ++s) pre += segs2[cl * 33 + s];
        float run = suf;
#pragma unroll
        for (int q = 15; q >= 0; --q) { run += v1[q]; v1[q] = run; }   // inclusive suffix
        float run2 = pre;
#pragma unroll
        for (int q = 0; q < 16; ++q) { float tv = v2[q]; v2[q] = run2; run2 += tv; } // excl prefix
#pragma unroll
        for (int q4 = 0; q4 < 4; ++q4) {
            *(float4*)(p1 + q4 * 4) = make_float4(v1[q4 * 4], v1[q4 * 4 + 1], v1[q4 * 4 + 2], v1[q4 * 4 + 3]);
            *(float4*)(p2 + q4 * 4) = make_float4(v2[q4 * 4], v2[q4 * 4 + 1], v2[q4 * 4 + 2], v2[q4 * 4 + 3]);
        }
        if (seg == 31) tot2[cl] = run2;
    }
    __syncthreads();

    // Phase Q: query scan tables at k_i
    {
        const int cl = t & 7, ibase = t >> 3;
#pragma unroll
        for (int p = 0; p < 16; ++p) {
            int i = p * 32 + ibase;
            int k = g_k[bh * 512 + i];
            float az = g_aZ[bh * 512 + i];
            float bz = g_bZ[bh * 512 + i];
            float S1 = (k < 512) ? A1[cl * AP + k] : 0.f;
            float P2 = (k < 512) ? A2[cl * AP + k] : tot2[cl];
            yH[((size_t)(b * 512 + i) * 4 + head) * 64 + c0 + cl] = az * S1 + bz * P2;
        }
    }
}

// ---------------------------------------------------------------------------
// Kernel C: x[bn][c] = relu( mean_h yH[bn][h][c] + bias[c] )
// ---------------------------------------------------------------------------
__global__ __launch_bounds__(256) void finalize_kernel(const float* __restrict__ yH,
                                                       const float* __restrict__ bias,
                                                       float* __restrict__ x) {
    int idx = blockIdx.x * 256 + threadIdx.x;
    int bn = idx >> 4, c4 = idx & 15;
    const float* yp = yH + (size_t)bn * 256 + c4 * 4;
    float4 v0 = *(const float4*)(yp);
    float4 v1 = *(const float4*)(yp + 64);
    float4 v2 = *(const float4*)(yp + 128);
    float4 v3 = *(const float4*)(yp + 192);
    float4 bs = *(const float4*)(bias + c4 * 4);
    float4 o;
    o.x = fmaxf(0.25f * (v0.x + v1.x + v2.x + v3.x) + bs.x, 0.f);
    o.y = fmaxf(0.25f * (v0.y + v1.y + v2.y + v3.y) + bs.y, 0.f);
    o.z = fmaxf(0.25f * (v0.z + v1.z + v2.z + v3.z) + bs.z, 0.f);
    o.w = fmaxf(0.25f * (v0.w + v1.w + v2.w + v3.w) + bs.w, 0.f);
    *(float4*)(x + (size_t)bn * 64 + c4 * 4) = o;
}

// ---------------------------------------------------------------------------
// Kernel D: out[b][d] = (mean_n x[b][n][:]) . readout_w[d][:] + readout_b[d]
// ---------------------------------------------------------------------------
__global__ __launch_bounds__(256) void readout_kernel(const float* __restrict__ x,
                                                      const float* __restrict__ rw,
                                                      const float* __restrict__ rb,
                                                      float* __restrict__ out) {
    __shared__ float red[4][64];
    __shared__ float pooled[64];
    int b = blockIdx.x, t = threadIdx.x;
    int c = t & 63, q = t >> 6;
    float acc = 0.f;
    for (int n = q; n < 512; n += 4) acc += x[((size_t)b * 512 + n) * 64 + c];
    red[q][c] = acc;
    __syncthreads();
    if (t < 64) pooled[t] = (red[0][t] + red[1][t] + red[2][t] + red[3][t]) * (1.0f / 512.0f);
    __syncthreads();
    if (t < 64) {
        float a = rb[t];
        for (int cc = 0; cc < 64; ++cc) a += pooled[cc] * rw[t * 64 + cc];
        out[b * 64 + t] = a;
    }
}

extern "C" void kernel_launch(void* const* d_in, const int* in_sizes, int n_in,
                              void* d_out, int out_size, void* d_ws, size_t ws_size,
                              hipStream_t stream) {
    const float* emb       = (const float*)d_in[0];
    const float* lin_w     = (const float*)d_in[1];
    const float* att_src   = (const float*)d_in[2];
    const float* att_dst   = (const float*)d_in[3];
    const float* conv_b    = (const float*)d_in[4];
    const float* readout_w = (const float*)d_in[5];
    const float* readout_b = (const float*)d_in[6];
    float* out = (float*)d_out;

    float* ws   = (float*)d_ws;
    float* xbuf = ws;                  // 2,097,152 floats (8 MB)
    float* hbuf = ws + 2097152;        // 8,388,608 floats (32 MB)

    // Prep metadata overlaid on xbuf front (free between lin and finalize).
    int*   g_sidx = (int*)xbuf;                    // 131072 ints
    float* g_E1   = xbuf + 131072;
    float* g_E2   = xbuf + 262144;
    float* g_aZ   = xbuf + 393216;
    float* g_bZ   = xbuf + 524288;
    int*   g_k    = (int*)(xbuf + 655360);         // total 3 MB < 8 MB

    for (int l = 0; l < 3; ++l) {
        const float* xin = (l == 0) ? emb : xbuf;
        lin_kernel<<<512, 256, 0, stream>>>(xin, lin_w + (size_t)l * 16384, hbuf);
        attn_prep<<<256, 256, 0, stream>>>(hbuf, att_src + l * 256, att_dst + l * 256,
                                           g_sidx, g_E1, g_E2, g_aZ, g_bZ, g_k);
        attn_agg<<<2048, 256, 0, stream>>>(hbuf, g_sidx, g_E1, g_E2, g_aZ, g_bZ, g_k, hbuf);
        finalize_kernel<<<2048, 256, 0, stream>>>(hbuf, conv_b + l * 64, xbuf);
    }
    readout_kernel<<<64, 256, 0, stream>>>(xbuf, readout_w, readout_b, out);
}

// Round 4
// 321.941 us; speedup vs baseline: 1.3152x; 1.3152x over previous
//
#include <hip/hip_runtime.h>
#include <math.h>

// Problem constants (fixed by reference): B=64, N=512, D=64, H=4, C=64, L=3
// Workspace layout (floats):
//   xbuf [0 .. 2097152)        : layer activations x (B*N*64) = 8 MB
//     -- prep metadata (3 MB) overlaid at FRONT of xbuf between lin (reads x)
//        and finalize (rewrites x); stream order makes it safe.
//   hbuf [2097152 .. 10485760) : h (B*N*H*C) = 32 MB; yH aliases h.

// ---------------------------------------------------------------------------
// Kernel A: h[gn][o] = sum_d x[gn][d] * W[o][d]
// 128n x 128o tile, XOR-swizzled LDS. d4 loop un-unrolled (R1: unroll spilled).
// ---------------------------------------------------------------------------
__global__ __launch_bounds__(256) void lin_kernel(const float* __restrict__ x,
                                                  const float* __restrict__ W,
                                                  float* __restrict__ h) {
    __shared__ float Ws[128 * 64];
    __shared__ float Xs[128 * 64];
    const int tid = threadIdx.x;
    const int nblk = blockIdx.x >> 1;
    const int o0 = (blockIdx.x & 1) * 128;
    const int gn0 = nblk * 128;

#pragma unroll
    for (int q = 0; q < 8; ++q) {
        int flat = q * 256 + tid;
        int row = flat >> 4, d4 = flat & 15;
        float4 v = *(const float4*)(W + (size_t)(o0 + row) * 64 + d4 * 4);
        *(float4*)(Ws + row * 64 + ((d4 ^ ((row >> 3) & 7)) << 2)) = v;
    }
#pragma unroll
    for (int q = 0; q < 8; ++q) {
        int flat = q * 256 + tid;
        int row = flat >> 4, d4 = flat & 15;
        float4 v = *(const float4*)(x + (size_t)(gn0 + row) * 64 + d4 * 4);
        *(float4*)(Xs + row * 64 + ((d4 ^ (row & 7)) << 2)) = v;
    }
    __syncthreads();

    const int og = tid >> 4;
    const int ng = tid & 15;
    const int wsw = og & 7;
    const int xsw = ng & 7;
    float acc[8][8];
#pragma unroll
    for (int k = 0; k < 8; ++k)
#pragma unroll
        for (int j = 0; j < 8; ++j) acc[k][j] = 0.f;

#pragma unroll 1
    for (int d4 = 0; d4 < 16; ++d4) {
        float4 x4[8];
#pragma unroll
        for (int j = 0; j < 8; ++j)
            x4[j] = *(const float4*)(Xs + (ng + 16 * j) * 64 + ((d4 ^ xsw) << 2));
#pragma unroll
        for (int k = 0; k < 8; ++k) {
            float4 w = *(const float4*)(Ws + (og * 8 + k) * 64 + ((d4 ^ wsw) << 2));
#pragma unroll
            for (int j = 0; j < 8; ++j)
                acc[k][j] += w.x * x4[j].x + w.y * x4[j].y +
                             w.z * x4[j].z + w.w * x4[j].w;
        }
    }

#pragma unroll
    for (int j = 0; j < 8; ++j) {
        int gn = gn0 + ng + 16 * j;
        float* dst = h + (size_t)gn * 256 + o0 + og * 8;
        *(float4*)(dst) = make_float4(acc[0][j], acc[1][j], acc[2][j], acc[3][j]);
        *(float4*)(dst + 4) = make_float4(acc[4][j], acc[5][j], acc[6][j], acc[7][j]);
    }
}

// ---------------------------------------------------------------------------
// Kernel B1: attn_prep v2 — per (b,head). Shuffle-based bitonic sort (2
// consecutive elements/thread: j=1 in-reg, j<=64 shfl_xor, j in {128,256} via
// LDS -> only 3 barrier-stages vs 45). Wave-shfl scans for z1suf/z2pre.
// ---------------------------------------------------------------------------
__global__ __launch_bounds__(256) void attn_prep(const float* __restrict__ h,
                                                 const float* __restrict__ att_src,
                                                 const float* __restrict__ att_dst,
                                                 int* __restrict__ g_sidx,
                                                 float* __restrict__ g_E1,
                                                 float* __restrict__ g_E2,
                                                 float* __restrict__ g_aZ,
                                                 float* __restrict__ g_bZ,
                                                 int* __restrict__ g_k) {
    const int bh = blockIdx.x;
    const int b = bh >> 2;
    const int head = bh & 3;
    const int t = threadIdx.x;
    const int lane = t & 63;
    const int wid = t >> 6;

    __shared__ float att_s[64], att_d[64];
    __shared__ float s_val[512];
    __shared__ int   s_idxE[512];
    __shared__ float dArr[512];
    __shared__ float z1suf[513], z2pre[513];
    __shared__ float wred[8];

    if (t < 64) att_s[t] = att_src[head * 64 + t];
    else if (t < 128) att_d[t - 64] = att_dst[head * 64 + (t - 64)];
    __syncthreads();

    // Dot products (coalesced-ish rows t, t+256)
    for (int rr = 0; rr < 2; ++rr) {
        int j = t + rr * 256;
        const float* hrow = h + ((size_t)(b * 512 + j) * 4 + head) * 64;
        float as = 0.f, ad = 0.f;
#pragma unroll
        for (int d4 = 0; d4 < 16; ++d4) {
            float4 hv = *(const float4*)(hrow + d4 * 4);
            float4 sv = *(const float4*)(att_s + d4 * 4);
            float4 dv = *(const float4*)(att_d + d4 * 4);
            as += hv.x * sv.x + hv.y * sv.y + hv.z * sv.z + hv.w * sv.w;
            ad += hv.x * dv.x + hv.y * dv.y + hv.z * dv.z + hv.w * dv.w;
        }
        s_val[j] = as; dArr[j] = ad;
    }
    __syncthreads();

    // Bitonic sort ascending; thread t holds positions 2t, 2t+1.
    float v0 = s_val[2 * t], v1 = s_val[2 * t + 1];
    int id0 = 2 * t, id1 = 2 * t + 1;
    for (int k = 2; k <= 512; k <<= 1) {
        for (int j = k >> 1; j >= 1; j >>= 1) {
            bool asc = ((t & (k >> 1)) == 0);   // ((2t)&k)==0
            if (j == 1) {
                bool sw = asc ? (v0 > v1) : (v0 < v1);
                if (sw) { float tv = v0; v0 = v1; v1 = tv; int ti = id0; id0 = id1; id1 = ti; }
            } else if (j <= 64) {
                int m = j >> 1;                 // 1..32, in-wave
                float w0 = __shfl_xor(v0, m, 64);
                int  wi0 = __shfl_xor(id0, m, 64);
                float w1 = __shfl_xor(v1, m, 64);
                int  wi1 = __shfl_xor(id1, m, 64);
                bool low = ((t & m) == 0);
                bool wantmin = (low == asc);
                if (wantmin ? (w0 < v0) : (w0 > v0)) { v0 = w0; id0 = wi0; }
                if (wantmin ? (w1 < v1) : (w1 > v1)) { v1 = w1; id1 = wi1; }
            } else {
                int m = j >> 1;                 // 64 or 128, cross-wave via LDS
                s_val[2 * t] = v0; s_val[2 * t + 1] = v1;
                s_idxE[2 * t] = id0; s_idxE[2 * t + 1] = id1;
                __syncthreads();
                int tp = t ^ m;
                float w0 = s_val[2 * tp], w1 = s_val[2 * tp + 1];
                int wi0 = s_idxE[2 * tp], wi1 = s_idxE[2 * tp + 1];
                bool low = ((t & m) == 0);
                bool wantmin = (low == asc);
                if (wantmin ? (w0 < v0) : (w0 > v0)) { v0 = w0; id0 = wi0; }
                if (wantmin ? (w1 < v1) : (w1 > v1)) { v1 = w1; id1 = wi1; }
                __syncthreads();
            }
        }
    }

    // Publish sorted values; exp factors from registers
    s_val[2 * t] = v0; s_val[2 * t + 1] = v1;
    __syncthreads();
    const float M = s_val[511];
    float e1_0 = __expf(v0 - M), e1_1 = __expf(v1 - M);
    float e2_0 = __expf(0.2f * (v0 - M)), e2_1 = __expf(0.2f * (v1 - M));
    *(float2*)(g_E1 + bh * 512 + 2 * t) = make_float2(e1_0, e1_1);
    *(float2*)(g_E2 + bh * 512 + 2 * t) = make_float2(e2_0, e2_1);
    *(int2*)(g_sidx + bh * 512 + 2 * t) = make_int2(id0, id1);

    // z-scans via wave shfl_up scan + cross-wave offsets
    float S1 = e1_0 + e1_1, S2 = e2_0 + e2_1;
    float i1 = S1, i2 = S2;
    for (int off = 1; off < 64; off <<= 1) {
        float u1 = __shfl_up(i1, off, 64);
        float u2 = __shfl_up(i2, off, 64);
        if (lane >= off) { i1 += u1; i2 += u2; }
    }
    if (lane == 63) { wred[wid] = i1; wred[4 + wid] = i2; }
    __syncthreads();
    float off1 = 0.f, off2 = 0.f;
    for (int w = 0; w < wid; ++w) { off1 += wred[w]; off2 += wred[4 + w]; }
    const float T1 = wred[0] + wred[1] + wred[2] + wred[3];
    const float T2 = wred[4] + wred[5] + wred[6] + wred[7];
    float pre1 = off1 + i1 - S1;      // exclusive prefix of E1 at pos 2t
    float pre2 = off2 + i2 - S2;
    z1suf[2 * t] = T1 - pre1;
    z1suf[2 * t + 1] = T1 - pre1 - e1_0;
    z2pre[2 * t] = pre2;
    z2pre[2 * t + 1] = pre2 + e2_0;
    if (t == 0) { z1suf[512] = 0.f; z2pre[512] = T2; }
    __syncthreads();

    // Per-i: crossover + normalizer
    for (int rr = 0; rr < 2; ++rr) {
        int i = t + rr * 256;
        float d = dArr[i];
        int lo = 0, hi = 512;
        while (lo < hi) {
            int mid = (lo + hi) >> 1;
            if (d + s_val[mid] >= 0.f) hi = mid; else lo = mid + 1;
        }
        int k = lo;
        float g = d + M;
        float G = (g >= 0.f) ? g : 0.2f * g;   // denominator >= 1
        float al = __expf(g - G);
        float be = __expf(0.2f * g - G);
        float Z = al * z1suf[k] + be * z2pre[k];
        float inv = 1.0f / Z;
        g_aZ[bh * 512 + i] = al * inv;
        g_bZ[bh * 512 + i] = be * inv;
        g_k[bh * 512 + i]  = k;
    }
}

// ---------------------------------------------------------------------------
// Kernel B2: attn_agg v2 — 16 channels/block (grid 1024). 64-B aligned h
// gather held in registers; ONE 33-KB LDS table used twice (suffix/E1 pass
// then prefix/E2 pass) -> ~39 KB LDS, 4 blocks/CU. XCD swizzle: blockIdx =
// q*64 + b so all 16 blocks of a batch share an XCD (h fetched once).
// yH aliases h: all h reads (phase 0) precede yH writes (end), block-local.
// ---------------------------------------------------------------------------
#define APW 516
__global__ __launch_bounds__(256) void attn_agg(const float* __restrict__ h,
                                                const int* __restrict__ g_sidx,
                                                const float* __restrict__ g_E1,
                                                const float* __restrict__ g_E2,
                                                const float* __restrict__ g_aZ,
                                                const float* __restrict__ g_bZ,
                                                const int* __restrict__ g_k,
                                                float* __restrict__ yH) {
    const int b = blockIdx.x & 63;
    const int q = blockIdx.x >> 6;       // 0..15
    const int head = q >> 2;
    const int cg = q & 3;
    const int bh = b * 4 + head;
    const int c0 = cg * 16;
    const int t = threadIdx.x;

    __shared__ float A[16 * APW];        // 33 KB, reused for both passes
    __shared__ float segs[16 * 17];
    __shared__ float tot[16];
    __shared__ int   kA[512];
    __shared__ float aZs[512], bZs[512];

    // Phase 0: metadata -> LDS; gather h (64-B aligned) -> registers
    float e1r[2], e2r[2], hv[2][16];
    for (int rr = 0; rr < 2; ++rr) {
        int r = t + rr * 256;
        int j = g_sidx[bh * 512 + r];
        e1r[rr] = g_E1[bh * 512 + r];
        e2r[rr] = g_E2[bh * 512 + r];
        kA[r]  = g_k[bh * 512 + r];
        aZs[r] = g_aZ[bh * 512 + r];
        bZs[r] = g_bZ[bh * 512 + r];
        const float* hp = h + ((size_t)(b * 512 + j) * 4 + head) * 64 + c0;
#pragma unroll
        for (int q4 = 0; q4 < 4; ++q4) {
            float4 v = *(const float4*)(hp + q4 * 4);
            hv[rr][q4 * 4 + 0] = v.x; hv[rr][q4 * 4 + 1] = v.y;
            hv[rr][q4 * 4 + 2] = v.z; hv[rr][q4 * 4 + 3] = v.w;
        }
    }
    __syncthreads();

    // ---- Pass A: suffix table of E1*h ----
    for (int rr = 0; rr < 2; ++rr) {
        int r = t + rr * 256;
#pragma unroll
        for (int c = 0; c < 16; ++c) A[c * APW + r] = e1r[rr] * hv[rr][c];
    }
    __syncthreads();
    {
        int ch = t & 15, seg = t >> 4;       // 16 segs x 32 rows
        float* base = A + ch * APW + seg * 32;
        float v[32];
#pragma unroll
        for (int q4 = 0; q4 < 8; ++q4) {
            float4 a = *(const float4*)(base + q4 * 4);
            v[q4 * 4] = a.x; v[q4 * 4 + 1] = a.y; v[q4 * 4 + 2] = a.z; v[q4 * 4 + 3] = a.w;
        }
        float s = 0.f;
#pragma unroll
        for (int i = 0; i < 32; ++i) s += v[i];
        segs[ch * 17 + seg] = s;
        __syncthreads();
        float suf = 0.f;
        for (int s2 = seg + 1; s2 < 16; ++s2) suf += segs[ch * 17 + s2];
        float run = suf;
#pragma unroll
        for (int i = 31; i >= 0; --i) { run += v[i]; v[i] = run; }   // inclusive suffix
#pragma unroll
        for (int q4 = 0; q4 < 8; ++q4)
            *(float4*)(base + q4 * 4) = make_float4(v[q4 * 4], v[q4 * 4 + 1], v[q4 * 4 + 2], v[q4 * 4 + 3]);
    }
    __syncthreads();
    float part[32];
    {
        int cl = t & 15, ibase = t >> 4;
#pragma unroll
        for (int p = 0; p < 32; ++p) {
            int i = p * 16 + ibase;
            int k = kA[i];
            float S1v = (k < 512) ? A[cl * APW + k] : 0.f;
            part[p] = aZs[i] * S1v;
        }
    }
    __syncthreads();

    // ---- Pass B: exclusive-prefix table of E2*h ----
    for (int rr = 0; rr < 2; ++rr) {
        int r = t + rr * 256;
#pragma unroll
        for (int c = 0; c < 16; ++c) A[c * APW + r] = e2r[rr] * hv[rr][c];
    }
    __syncthreads();
    {
        int ch = t & 15, seg = t >> 4;
        float* base = A + ch * APW + seg * 32;
        float v[32];
#pragma unroll
        for (int q4 = 0; q4 < 8; ++q4) {
            float4 a = *(const float4*)(base + q4 * 4);
            v[q4 * 4] = a.x; v[q4 * 4 + 1] = a.y; v[q4 * 4 + 2] = a.z; v[q4 * 4 + 3] = a.w;
        }
        float s = 0.f;
#pragma unroll
        for (int i = 0; i < 32; ++i) s += v[i];
        segs[ch * 17 + seg] = s;
        __syncthreads();
        float pre = 0.f;
        for (int s2 = 0; s2 < seg; ++s2) pre += segs[ch * 17 + s2];
        float run2 = pre;
#pragma unroll
        for (int i = 0; i < 32; ++i) { float tv = v[i]; v[i] = run2; run2 += tv; } // excl prefix
#pragma unroll
        for (int q4 = 0; q4 < 8; ++q4)
            *(float4*)(base + q4 * 4) = make_float4(v[q4 * 4], v[q4 * 4 + 1], v[q4 * 4 + 2], v[q4 * 4 + 3]);
        if (seg == 15) tot[ch] = run2;
    }
    __syncthreads();
    {
        int cl = t & 15, ibase = t >> 4;
#pragma unroll
        for (int p = 0; p < 32; ++p) {
            int i = p * 16 + ibase;
            int k = kA[i];
            float P2 = (k < 512) ? A[cl * APW + k] : tot[cl];
            float val = part[p] + bZs[i] * P2;
            yH[((size_t)(b * 512 + i) * 4 + head) * 64 + c0 + cl] = val;
        }
    }
}

// ---------------------------------------------------------------------------
// Kernel C: x[bn][c] = relu( mean_h yH[bn][h][c] + bias[c] )
// ---------------------------------------------------------------------------
__global__ __launch_bounds__(256) void finalize_kernel(const float* __restrict__ yH,
                                                       const float* __restrict__ bias,
                                                       float* __restrict__ x) {
    int idx = blockIdx.x * 256 + threadIdx.x;
    int bn = idx >> 4, c4 = idx & 15;
    const float* yp = yH + (size_t)bn * 256 + c4 * 4;
    float4 v0 = *(const float4*)(yp);
    float4 v1 = *(const float4*)(yp + 64);
    float4 v2 = *(const float4*)(yp + 128);
    float4 v3 = *(const float4*)(yp + 192);
    float4 bs = *(const float4*)(bias + c4 * 4);
    float4 o;
    o.x = fmaxf(0.25f * (v0.x + v1.x + v2.x + v3.x) + bs.x, 0.f);
    o.y = fmaxf(0.25f * (v0.y + v1.y + v2.y + v3.y) + bs.y, 0.f);
    o.z = fmaxf(0.25f * (v0.z + v1.z + v2.z + v3.z) + bs.z, 0.f);
    o.w = fmaxf(0.25f * (v0.w + v1.w + v2.w + v3.w) + bs.w, 0.f);
    *(float4*)(x + (size_t)bn * 64 + c4 * 4) = o;
}

// ---------------------------------------------------------------------------
// Kernel D: out[b][d] = (mean_n x[b][n][:]) . readout_w[d][:] + readout_b[d]
// ---------------------------------------------------------------------------
__global__ __launch_bounds__(256) void readout_kernel(const float* __restrict__ x,
                                                      const float* __restrict__ rw,
                                                      const float* __restrict__ rb,
                                                      float* __restrict__ out) {
    __shared__ float red[4][64];
    __shared__ float pooled[64];
    int b = blockIdx.x, t = threadIdx.x;
    int c = t & 63, q = t >> 6;
    float acc = 0.f;
    for (int n = q; n < 512; n += 4) acc += x[((size_t)b * 512 + n) * 64 + c];
    red[q][c] = acc;
    __syncthreads();
    if (t < 64) pooled[t] = (red[0][t] + red[1][t] + red[2][t] + red[3][t]) * (1.0f / 512.0f);
    __syncthreads();
    if (t < 64) {
        float a = rb[t];
        for (int cc = 0; cc < 64; ++cc) a += pooled[cc] * rw[t * 64 + cc];
        out[b * 64 + t] = a;
    }
}

extern "C" void kernel_launch(void* const* d_in, const int* in_sizes, int n_in,
                              void* d_out, int out_size, void* d_ws, size_t ws_size,
                              hipStream_t stream) {
    const float* emb       = (const float*)d_in[0];
    const float* lin_w     = (const float*)d_in[1];
    const float* att_src   = (const float*)d_in[2];
    const float* att_dst   = (const float*)d_in[3];
    const float* conv_b    = (const float*)d_in[4];
    const float* readout_w = (const float*)d_in[5];
    const float* readout_b = (const float*)d_in[6];
    float* out = (float*)d_out;

    float* ws   = (float*)d_ws;
    float* xbuf = ws;                  // 2,097,152 floats (8 MB)
    float* hbuf = ws + 2097152;        // 8,388,608 floats (32 MB)

    int*   g_sidx = (int*)xbuf;
    float* g_E1   = xbuf + 131072;
    float* g_E2   = xbuf + 262144;
    float* g_aZ   = xbuf + 393216;
    float* g_bZ   = xbuf + 524288;
    int*   g_k    = (int*)(xbuf + 655360);

    for (int l = 0; l < 3; ++l) {
        const float* xin = (l == 0) ? emb : xbuf;
        lin_kernel<<<512, 256, 0, stream>>>(xin, lin_w + (size_t)l * 16384, hbuf);
        attn_prep<<<256, 256, 0, stream>>>(hbuf, att_src + l * 256, att_dst + l * 256,
                                           g_sidx, g_E1, g_E2, g_aZ, g_bZ, g_k);
        attn_agg<<<1024, 256, 0, stream>>>(hbuf, g_sidx, g_E1, g_E2, g_aZ, g_bZ, g_k, hbuf);
        finalize_kernel<<<2048, 256, 0, stream>>>(hbuf, conv_b + l * 64, xbuf);
    }
    readout_kernel<<<64, 256, 0, stream>>>(xbuf, readout_w, readout_b, out);
}